// Round 1
// baseline (781.320 us; speedup 1.0000x reference)
//
#include <hip/hip_runtime.h>
#include <math.h>

#define N_TOTAL 40960
#define M_EV    4096
#define CIN     64
#define SDIM    4
#define PDIM    64
#define KNN     32
#define COUT    128
#define FEAT    192   // CIN + 2*PDIM

// ---------------------------------------------------------------------------
// Kernel 1: space = x@W_space + b_space  [N,4];  prop = x@W_prop + b_prop [N,64]
// block 256 handles 16 rows. 64 threads per row-group, 4 rows per thread.
// ---------------------------------------------------------------------------
__device__ __forceinline__ float dot4f(float4 a, float4 b) {
    return fmaf(a.w, b.w, fmaf(a.z, b.z, fmaf(a.y, b.y, a.x * b.x)));
}

__global__ __launch_bounds__(256) void k_linear(
    const float* __restrict__ x,
    const float* __restrict__ Wp, const float* __restrict__ bp,
    const float* __restrict__ Ws, const float* __restrict__ bs,
    float* __restrict__ prop, float* __restrict__ space)
{
    __shared__ float xs[16 * 64];
    const int t = threadIdx.x;
    const int rowbase = blockIdx.x * 16;

    // stage 16x64 x-tile (1024 floats, 4 per thread, coalesced float4)
    {
        float4 v = *(const float4*)(x + rowbase * 64 + t * 4);
        *(float4*)(xs + t * 4) = v;
    }
    __syncthreads();

    const int j  = t & 63;
    const int rg = t >> 6;   // 0..3 -> rows rg*4 .. rg*4+3
    float a0 = 0.f, a1 = 0.f, a2 = 0.f, a3 = 0.f;
    #pragma unroll 8
    for (int c = 0; c < 64; ++c) {
        float w = Wp[c * 64 + j];
        a0 = fmaf(xs[(rg * 4 + 0) * 64 + c], w, a0);
        a1 = fmaf(xs[(rg * 4 + 1) * 64 + c], w, a1);
        a2 = fmaf(xs[(rg * 4 + 2) * 64 + c], w, a2);
        a3 = fmaf(xs[(rg * 4 + 3) * 64 + c], w, a3);
    }
    const float bj = bp[j];
    prop[(rowbase + rg * 4 + 0) * 64 + j] = a0 + bj;
    prop[(rowbase + rg * 4 + 1) * 64 + j] = a1 + bj;
    prop[(rowbase + rg * 4 + 2) * 64 + j] = a2 + bj;
    prop[(rowbase + rg * 4 + 3) * 64 + j] = a3 + bj;

    // space: threads 0..63 -> (row r = t/4, coord s = t%4)
    if (t < 64) {
        const int r = t >> 2, s = t & 3;
        float a = 0.f;
        #pragma unroll 8
        for (int c = 0; c < 64; ++c)
            a = fmaf(xs[r * 64 + c], Ws[c * 4 + s], a);
        space[(rowbase + r) * 4 + s] = a + bs[s];
    }
}

// ---------------------------------------------------------------------------
// Kernel 2: exact brute-force kNN per event (K=32 smallest d2, tie -> lower idx)
// 1 thread = 1 query. Buffered-append (cheap, exec-masked) + wave-collective
// packed drain (replace-max + rescan, lane-parallel) to avoid the 64x
// divergence amplification of per-candidate rescans.
// Output transposed: knn_idx[e*N + q], knn_w[e*N + q]  (coalesced both ends).
// ---------------------------------------------------------------------------
#define KBLK 128
#define TILE 512
#define QCAP 16

__global__ __launch_bounds__(KBLK) void k_knn(
    const float* __restrict__ space,
    int* __restrict__ knn_idx, float* __restrict__ knn_w)
{
    __shared__ float4 s_c[TILE];
    __shared__ float  s_sq[TILE];
    __shared__ float  s_ld[KNN * KBLK];   // top-K dists, [entry][lane]
    __shared__ int    s_li[KNN * KBLK];   // top-K local cand indices
    __shared__ float  s_bd[QCAP * KBLK];  // append buffer dists
    __shared__ int    s_bi[QCAP * KBLK];  // append buffer idx

    const int t  = threadIdx.x;
    const int q  = blockIdx.x * KBLK + t;          // global query row
    const int ev = q >> 12;                        // /4096
    const int ebase = ev * M_EV;

    const float4 qc = *(const float4*)(space + (size_t)q * 4);
    const float sqq = dot4f(qc, qc);

    #pragma unroll
    for (int e = 0; e < KNN; ++e) s_ld[e * KBLK + t] = INFINITY;

    float thr = INFINITY;        // stale admission threshold
    float curmax = INFINITY;     // exact current 32nd-smallest (or INF)
    int   maxpos = 0;
    int   cnt = 0;               // per-lane buffer cursor

    auto drain = [&]() {
        for (int b = 0; b < cnt; ++b) {            // lane-packed: all lanes work own queue
            float d = s_bd[b * KBLK + t];
            if (d < curmax) {
                s_ld[maxpos * KBLK + t] = d;
                s_li[maxpos * KBLK + t] = s_bi[b * KBLK + t];
                float m = -INFINITY; int mp = 0;
                #pragma unroll
                for (int e = 0; e < KNN; ++e) {
                    float v = s_ld[e * KBLK + t];
                    if (v > m) { m = v; mp = e; }
                }
                curmax = m; maxpos = mp;
            }
        }
        cnt = 0;
        thr = curmax;
    };

    for (int tile = 0; tile < M_EV / TILE; ++tile) {
        __syncthreads();
        #pragma unroll
        for (int u = 0; u < TILE / KBLK; ++u) {
            int ci = u * KBLK + t;
            float4 c = *(const float4*)(space + (size_t)(ebase + tile * TILE + ci) * 4);
            s_c[ci]  = c;
            s_sq[ci] = dot4f(c, c);
        }
        __syncthreads();

        for (int jj = 0; jj < TILE; ++jj) {
            float4 c  = s_c[jj];
            float  d2 = fmaf(-2.0f, dot4f(qc, c), sqq + s_sq[jj]);
            if (d2 < thr) {                         // strict < : keeps earlier index on ties
                s_bd[cnt * KBLK + t] = d2;
                s_bi[cnt * KBLK + t] = tile * TILE + jj;
                cnt++;
            }
            if (__any(cnt >= QCAP)) drain();        // wave-collective
        }
    }
    drain();                                        // flush remainder

    #pragma unroll
    for (int e = 0; e < KNN; ++e) {
        float d  = s_ld[e * KBLK + t];
        int   ix = s_li[e * KBLK + t];
        knn_idx[e * N_TOTAL + q] = ebase + ix;
        knn_w[e * N_TOTAL + q]   = __expf(-10.0f * fmaxf(d, 0.0f));
    }
}

// ---------------------------------------------------------------------------
// Kernel 3: gathered = prop[nidx] * w ; fmean = mean_k ; fmax = max_k
// block 256 = 4 queries x 64 p-lanes. prop rows are L2-resident (1 MB/event).
// ---------------------------------------------------------------------------
__global__ __launch_bounds__(256) void k_agg(
    const float* __restrict__ prop,
    const int* __restrict__ knn_idx, const float* __restrict__ knn_w,
    float* __restrict__ fmean, float* __restrict__ fmax)
{
    const int t = threadIdx.x;
    const int p = t & 63;
    const int q = blockIdx.x * 4 + (t >> 6);

    float acc = 0.f, mx = -INFINITY;
    #pragma unroll 8
    for (int e = 0; e < KNN; ++e) {
        int   ix = knn_idx[e * N_TOTAL + q];   // broadcast across 64 lanes
        float w  = knn_w[e * N_TOTAL + q];
        float g  = w * prop[(size_t)ix * 64 + p];
        acc += g;
        mx = fmaxf(mx, g);
    }
    fmean[(size_t)q * 64 + p] = acc * (1.0f / 32.0f);
    fmax[(size_t)q * 64 + p]  = mx;
}

// ---------------------------------------------------------------------------
// Kernel 4: out = relu([x | fmean | fmax] @ W_out + b_out)   [N,128]
// block 256 computes 16 rows x 128 cols; 8 outputs/thread; feat tile in LDS.
// ---------------------------------------------------------------------------
__global__ __launch_bounds__(256) void k_out(
    const float* __restrict__ x,
    const float* __restrict__ fmean, const float* __restrict__ fmax,
    const float* __restrict__ Wo, const float* __restrict__ bo,
    float* __restrict__ out)
{
    __shared__ float fs[16 * FEAT];
    const int t = threadIdx.x;
    const int qbase = blockIdx.x * 16;

    #pragma unroll
    for (int u = 0; u < 12; ++u) {               // 16*192 = 3072 = 12*256
        int f = u * 256 + t;
        int r = f / FEAT;
        int i = f - r * FEAT;
        float v;
        if (i < 64)        v = x[(size_t)(qbase + r) * 64 + i];
        else if (i < 128)  v = fmean[(size_t)(qbase + r) * 64 + (i - 64)];
        else               v = fmax[(size_t)(qbase + r) * 64 + (i - 128)];
        fs[f] = v;
    }
    __syncthreads();

    const int c  = t & 127;
    const int rg = t >> 7;                       // 0..1 -> rows rg*8 .. rg*8+7
    float acc[8] = {0.f, 0.f, 0.f, 0.f, 0.f, 0.f, 0.f, 0.f};

    #pragma unroll 4
    for (int i = 0; i < FEAT; ++i) {
        float w = Wo[i * 128 + c];
        #pragma unroll
        for (int r = 0; r < 8; ++r)
            acc[r] = fmaf(fs[(rg * 8 + r) * FEAT + i], w, acc[r]);
    }
    const float bc = bo[c];
    #pragma unroll
    for (int r = 0; r < 8; ++r)
        out[(size_t)(qbase + rg * 8 + r) * 128 + c] = fmaxf(acc[r] + bc, 0.0f);
}

// ---------------------------------------------------------------------------
extern "C" void kernel_launch(void* const* d_in, const int* in_sizes, int n_in,
                              void* d_out, int out_size, void* d_ws, size_t ws_size,
                              hipStream_t stream) {
    const float* x  = (const float*)d_in[0];
    // d_in[1] = row_splits (uniform, unused)
    const float* Ws = (const float*)d_in[2];
    const float* bs = (const float*)d_in[3];
    const float* Wp = (const float*)d_in[4];
    const float* bp = (const float*)d_in[5];
    const float* Wo = (const float*)d_in[6];
    const float* bo = (const float*)d_in[7];
    float* out = (float*)d_out;

    float* space = (float*)d_ws;                       // N*4
    float* prop  = space + (size_t)N_TOTAL * 4;        // N*64
    int*   kidx  = (int*)(prop + (size_t)N_TOTAL * 64);// 32*N
    float* kw    = (float*)(kidx + (size_t)KNN * N_TOTAL); // 32*N
    float* fmean = kw + (size_t)KNN * N_TOTAL;         // N*64
    float* fmax  = fmean + (size_t)N_TOTAL * 64;       // N*64

    k_linear<<<N_TOTAL / 16, 256, 0, stream>>>(x, Wp, bp, Ws, bs, prop, space);
    k_knn   <<<N_TOTAL / KBLK, KBLK, 0, stream>>>(space, kidx, kw);
    k_agg   <<<N_TOTAL / 4, 256, 0, stream>>>(prop, kidx, kw, fmean, fmax);
    k_out   <<<N_TOTAL / 16, 256, 0, stream>>>(x, fmean, fmax, Wo, bo, out);
}

// Round 2
// 545.127 us; speedup vs baseline: 1.4333x; 1.4333x over previous
//
#include <hip/hip_runtime.h>
#include <math.h>

#define N_TOTAL 40960
#define M_EV    4096
#define CIN     64
#define SDIM    4
#define PDIM    64
#define KNN     32
#define COUT    128
#define FEAT    192   // CIN + 2*PDIM

__device__ __forceinline__ float dot4f(float4 a, float4 b) {
    return fmaf(a.w, b.w, fmaf(a.z, b.z, fmaf(a.y, b.y, a.x * b.x)));
}

// ---------------------------------------------------------------------------
// Kernel 1: space = x@W_space + b_space  [N,4];  prop = x@W_prop + b_prop [N,64]
// ---------------------------------------------------------------------------
__global__ __launch_bounds__(256) void k_linear(
    const float* __restrict__ x,
    const float* __restrict__ Wp, const float* __restrict__ bp,
    const float* __restrict__ Ws, const float* __restrict__ bs,
    float* __restrict__ prop, float* __restrict__ space)
{
    __shared__ float xs[16 * 64];
    const int t = threadIdx.x;
    const int rowbase = blockIdx.x * 16;

    {
        float4 v = *(const float4*)(x + rowbase * 64 + t * 4);
        *(float4*)(xs + t * 4) = v;
    }
    __syncthreads();

    const int j  = t & 63;
    const int rg = t >> 6;
    float a0 = 0.f, a1 = 0.f, a2 = 0.f, a3 = 0.f;
    #pragma unroll 8
    for (int c = 0; c < 64; ++c) {
        float w = Wp[c * 64 + j];
        a0 = fmaf(xs[(rg * 4 + 0) * 64 + c], w, a0);
        a1 = fmaf(xs[(rg * 4 + 1) * 64 + c], w, a1);
        a2 = fmaf(xs[(rg * 4 + 2) * 64 + c], w, a2);
        a3 = fmaf(xs[(rg * 4 + 3) * 64 + c], w, a3);
    }
    const float bj = bp[j];
    prop[(rowbase + rg * 4 + 0) * 64 + j] = a0 + bj;
    prop[(rowbase + rg * 4 + 1) * 64 + j] = a1 + bj;
    prop[(rowbase + rg * 4 + 2) * 64 + j] = a2 + bj;
    prop[(rowbase + rg * 4 + 3) * 64 + j] = a3 + bj;

    if (t < 64) {
        const int r = t >> 2, s = t & 3;
        float a = 0.f;
        #pragma unroll 8
        for (int c = 0; c < 64; ++c)
            a = fmaf(xs[r * 64 + c], Ws[c * 4 + s], a);
        space[(rowbase + r) * 4 + s] = a + bs[s];
    }
}

// ---------------------------------------------------------------------------
// Kernel 2: exact kNN. Block = 256 thr = 4 waves; wave w scans candidate
// chunk w (1024) for queries qbase..qbase+63 (one per lane). Register top-32
// lists, buffered-append + wave-packed drain, cross-split threshold sharing
// via LDS atomicMin (d2>=0 -> float bits monotone). In-block merge at end.
// ---------------------------------------------------------------------------
#define QB    64
#define NW    4
#define CHUNK (M_EV / NW)   // 1024
#define KTILE 128
#define QCAP  16

__device__ __forceinline__ void list_insert(float (&ld)[KNN], int (&li)[KNN],
                                            float &curmax, int &maxpos,
                                            float d, int ix)
{
    #pragma unroll
    for (int e = 0; e < KNN; ++e)
        if (e == maxpos) { ld[e] = d; li[e] = ix; }
    float m = ld[0]; int mp = 0;
    #pragma unroll
    for (int e = 1; e < KNN; ++e)
        if (ld[e] > m) { m = ld[e]; mp = e; }
    curmax = m; maxpos = mp;
}

// LDS map (49408 B -> 3 blocks/CU):
//   scan phase : s_c 8192 | s_sq 2048 | s_bd 16384 | s_bi 16384 | (pad) | s_thr 256
//   merge phase: s_pd 24576 | s_pi 24576 (alias scan area, after barrier)
#define SMEM_BYTES 49408

__global__ __launch_bounds__(256) void k_knn(
    const float4* __restrict__ space4,
    int* __restrict__ knn_idx, float* __restrict__ knn_w)
{
    __shared__ char smem[SMEM_BYTES];
    float4*   s_c   = (float4*)smem;                 // NW*KTILE*16
    float*    s_sq  = (float*)(smem + 8192);         // NW*KTILE*4
    float*    s_bd  = (float*)(smem + 10240);        // QCAP*256*4
    int*      s_bi  = (int*)(smem + 26624);          // QCAP*256*4
    unsigned* s_thr = (unsigned*)(smem + 49152);     // QB*4
    float*    s_pd  = (float*)smem;                  // 3*KNN*QB*4
    int*      s_pi  = (int*)(smem + 24576);          // 3*KNN*QB*4

    const int t = threadIdx.x;
    const int w = t >> 6;
    const int l = t & 63;
    const int qbase = blockIdx.x * QB;
    const int q = qbase + l;
    const int ebase = (qbase >> 12) << 12;           // uniform: block in one event

    if (t < QB) s_thr[t] = 0x7f800000u;              // +inf bits
    __syncthreads();

    const float4 qc = space4[q];
    const float sqq = dot4f(qc, qc);

    float ld[KNN]; int li[KNN];
    #pragma unroll
    for (int e = 0; e < KNN; ++e) { ld[e] = INFINITY; li[e] = 0; }
    float curmax = INFINITY; int maxpos = 0;
    float thrA = INFINITY;
    int cnt = 0;

    const int cbase0 = w * CHUNK;
    float4 n0 = space4[ebase + cbase0 + l];
    float4 n1 = space4[ebase + cbase0 + 64 + l];

    #pragma unroll 1
    for (int tb = 0; tb < CHUNK / KTILE; ++tb) {
        const int cbase = cbase0 + tb * KTILE;
        // stage tile (wave-private LDS region; no block barrier needed)
        s_c[w * KTILE + l]       = n0;  s_sq[w * KTILE + l]      = dot4f(n0, n0);
        s_c[w * KTILE + 64 + l]  = n1;  s_sq[w * KTILE + 64 + l] = dot4f(n1, n1);
        if (tb + 1 < CHUNK / KTILE) {
            n0 = space4[ebase + cbase + KTILE + l];
            n1 = space4[ebase + cbase + KTILE + 64 + l];
        }
        thrA = fminf(curmax, __uint_as_float(s_thr[l]));

        #pragma unroll 1
        for (int jj = 0; jj < KTILE; jj += 4) {
            float d[4];
            #pragma unroll
            for (int u = 0; u < 4; ++u) {
                float4 c = s_c[w * KTILE + jj + u];
                float sc = s_sq[w * KTILE + jj + u];
                d[u] = fmaf(-2.0f, dot4f(qc, c), sqq + sc);
            }
            #pragma unroll
            for (int u = 0; u < 4; ++u) {
                if (d[u] < thrA) {                   // strict <: earlier idx wins ties
                    s_bd[cnt * 256 + t] = d[u];
                    s_bi[cnt * 256 + t] = cbase + jj + u;
                    cnt++;
                }
            }
            if (__any(cnt > QCAP - 4)) {             // wave-collective packed drain
                #pragma unroll 1
                for (int b = 0; b < cnt; ++b) {
                    float dd = s_bd[b * 256 + t];
                    if (dd < curmax)
                        list_insert(ld, li, curmax, maxpos, dd, s_bi[b * 256 + t]);
                }
                cnt = 0;
                if (curmax < 1e37f)
                    atomicMin(&s_thr[l], __float_as_uint(fmaxf(curmax, 0.0f)));
                thrA = fminf(curmax, __uint_as_float(s_thr[l]));
            }
        }
    }
    // final drain
    #pragma unroll 1
    for (int b = 0; b < cnt; ++b) {
        float dd = s_bd[b * 256 + t];
        if (dd < curmax)
            list_insert(ld, li, curmax, maxpos, dd, s_bi[b * 256 + t]);
    }

    __syncthreads();                                 // scan LDS dead; alias as pool
    if (w > 0) {
        #pragma unroll
        for (int e = 0; e < KNN; ++e) {
            s_pd[((w - 1) * KNN + e) * QB + l] = ld[e];
            s_pi[((w - 1) * KNN + e) * QB + l] = li[e];
        }
    }
    __syncthreads();
    if (w == 0) {
        #pragma unroll 1
        for (int j = 0; j < 3 * KNN; ++j) {
            float dd = s_pd[j * QB + l];
            if (dd < curmax)
                list_insert(ld, li, curmax, maxpos, dd, s_pi[j * QB + l]);
        }
        #pragma unroll
        for (int e = 0; e < KNN; ++e) {
            knn_idx[e * N_TOTAL + q] = ebase + li[e];
            knn_w[e * N_TOTAL + q]   = __expf(-10.0f * fmaxf(ld[e], 0.0f));
        }
    }
}

// ---------------------------------------------------------------------------
// Kernel 3: weighted gather + mean/max over K
// ---------------------------------------------------------------------------
__global__ __launch_bounds__(256) void k_agg(
    const float* __restrict__ prop,
    const int* __restrict__ knn_idx, const float* __restrict__ knn_w,
    float* __restrict__ fmean, float* __restrict__ fmax)
{
    const int t = threadIdx.x;
    const int p = t & 63;
    const int q = blockIdx.x * 4 + (t >> 6);

    float acc = 0.f, mx = -INFINITY;
    #pragma unroll 8
    for (int e = 0; e < KNN; ++e) {
        int   ix = knn_idx[e * N_TOTAL + q];
        float w  = knn_w[e * N_TOTAL + q];
        float g  = w * prop[(size_t)ix * 64 + p];
        acc += g;
        mx = fmaxf(mx, g);
    }
    fmean[(size_t)q * 64 + p] = acc * (1.0f / 32.0f);
    fmax[(size_t)q * 64 + p]  = mx;
}

// ---------------------------------------------------------------------------
// Kernel 4: out = relu([x | fmean | fmax] @ W_out + b_out)
// ---------------------------------------------------------------------------
__global__ __launch_bounds__(256) void k_out(
    const float* __restrict__ x,
    const float* __restrict__ fmean, const float* __restrict__ fmax,
    const float* __restrict__ Wo, const float* __restrict__ bo,
    float* __restrict__ out)
{
    __shared__ float fs[16 * FEAT];
    const int t = threadIdx.x;
    const int qbase = blockIdx.x * 16;

    #pragma unroll
    for (int u = 0; u < 12; ++u) {
        int f = u * 256 + t;
        int r = f / FEAT;
        int i = f - r * FEAT;
        float v;
        if (i < 64)        v = x[(size_t)(qbase + r) * 64 + i];
        else if (i < 128)  v = fmean[(size_t)(qbase + r) * 64 + (i - 64)];
        else               v = fmax[(size_t)(qbase + r) * 64 + (i - 128)];
        fs[f] = v;
    }
    __syncthreads();

    const int c  = t & 127;
    const int rg = t >> 7;
    float acc[8] = {0.f, 0.f, 0.f, 0.f, 0.f, 0.f, 0.f, 0.f};

    #pragma unroll 4
    for (int i = 0; i < FEAT; ++i) {
        float w = Wo[i * 128 + c];
        #pragma unroll
        for (int r = 0; r < 8; ++r)
            acc[r] = fmaf(fs[(rg * 8 + r) * FEAT + i], w, acc[r]);
    }
    const float bc = bo[c];
    #pragma unroll
    for (int r = 0; r < 8; ++r)
        out[(size_t)(qbase + rg * 8 + r) * 128 + c] = fmaxf(acc[r] + bc, 0.0f);
}

// ---------------------------------------------------------------------------
extern "C" void kernel_launch(void* const* d_in, const int* in_sizes, int n_in,
                              void* d_out, int out_size, void* d_ws, size_t ws_size,
                              hipStream_t stream) {
    const float* x  = (const float*)d_in[0];
    const float* Ws = (const float*)d_in[2];
    const float* bs = (const float*)d_in[3];
    const float* Wp = (const float*)d_in[4];
    const float* bp = (const float*)d_in[5];
    const float* Wo = (const float*)d_in[6];
    const float* bo = (const float*)d_in[7];
    float* out = (float*)d_out;

    float* space = (float*)d_ws;
    float* prop  = space + (size_t)N_TOTAL * 4;
    int*   kidx  = (int*)(prop + (size_t)N_TOTAL * 64);
    float* kw    = (float*)(kidx + (size_t)KNN * N_TOTAL);
    float* fmean = kw + (size_t)KNN * N_TOTAL;
    float* fmax  = fmean + (size_t)N_TOTAL * 64;

    k_linear<<<N_TOTAL / 16, 256, 0, stream>>>(x, Wp, bp, Ws, bs, prop, space);
    k_knn   <<<N_TOTAL / QB, 256, 0, stream>>>((const float4*)space, kidx, kw);
    k_agg   <<<N_TOTAL / 4, 256, 0, stream>>>(prop, kidx, kw, fmean, fmax);
    k_out   <<<N_TOTAL / 16, 256, 0, stream>>>(x, fmean, fmax, Wo, bo, out);
}